// Round 1
// baseline (70.089 us; speedup 1.0000x reference)
//
#include <hip/hip_runtime.h>

#define BS   32
#define NMB  128
#define GS   80
#define NG   (GS * GS)
#define NANC 3
#define NC   80

typedef unsigned long long ull;

// merge two sorted key-triples -> smallest 3 (keys unique: (dist_bits<<32)|idx)
__device__ inline void merge3(ull& k0, ull& k1, ull& k2, ull b0, ull b1, ull b2) {
    ull a0 = k0, a1 = k1, a2 = k2;
    ull r0, r1, r2;
    if (a0 <= b0) { r0 = a0; a0 = a1; a1 = a2; a2 = ~0ull; }
    else          { r0 = b0; b0 = b1; b1 = b2; b2 = ~0ull; }
    if (a0 <= b0) { r1 = a0; a0 = a1; a1 = a2; }
    else          { r1 = b0; b0 = b1; b1 = b2; }
    r2 = (a0 <= b0) ? a0 : b0;
    k0 = r0; k1 = r1; k2 = r2;
}

// one wave per (b, gt): top-3 nearest cells by L1 distance; scatter claims
__global__ void k_topk(const float* __restrict__ gt_cxys,
                       const float* __restrict__ mask_gt,
                       int* __restrict__ topk,   // [BS*NMB*3]
                       int* __restrict__ cnt,    // [BS*NG]
                       int* __restrict__ agt)    // [BS*NG]
{
    int wid  = (blockIdx.x * blockDim.x + threadIdx.x) >> 6;
    int lane = threadIdx.x & 63;
    if (wid >= BS * NMB) return;
    int b = wid >> 7;          // / NMB (=128)
    int n = wid & (NMB - 1);
    float cx = gt_cxys[wid * 2 + 0];
    float cy = gt_cxys[wid * 2 + 1];

    ull k0 = ~0ull, k1 = ~0ull, k2 = ~0ull;
    int gx = lane, gy = 0;     // g = gy*GS + gx, stepping by 64 (< GS)
    for (int g = lane; g < NG; g += 64) {
        // EXACT reference arithmetic: |(grid+0.5) - c| summed x then y
        float d = fabsf((float)gx + 0.5f - cx) + fabsf((float)gy + 0.5f - cy);
        ull key = ((ull)__float_as_uint(d) << 32) | (unsigned)g;
        if (key < k2) {
            if (key < k1) { k2 = k1; if (key < k0) { k1 = k0; k0 = key; } else k1 = key; }
            else k2 = key;
        }
        gx += 64; if (gx >= GS) { gx -= GS; gy += 1; }
    }
    for (int off = 1; off < 64; off <<= 1) {
        ull b0 = __shfl_xor(k0, off);
        ull b1 = __shfl_xor(k1, off);
        ull b2 = __shfl_xor(k2, off);
        merge3(k0, k1, k2, b0, b1, b2);
    }
    if (lane == 0) {
        int i0 = (int)(unsigned)(k0 & 0xffffffffu);
        int i1 = (int)(unsigned)(k1 & 0xffffffffu);
        int i2 = (int)(unsigned)(k2 & 0xffffffffu);
        topk[wid * 3 + 0] = i0;
        topk[wid * 3 + 1] = i1;
        topk[wid * 3 + 2] = i2;
        if (mask_gt[wid] > 0.0f) {
            atomicAdd(&cnt[b * NG + i0], 1); agt[b * NG + i0] = n;
            atomicAdd(&cnt[b * NG + i1], 1); agt[b * NG + i1] = n;
            atomicAdd(&cnt[b * NG + i2], 1); agt[b * NG + i2] = n;
        }
    }
}

// one thread per (b, cell): resolve conflicts, gather targets, write box/fg/anc
__global__ void k_resolve(const float* __restrict__ gt_cls,
                          const float* __restrict__ gt_cxys,
                          const float* __restrict__ gt_whs,
                          const float* __restrict__ mask_gt,
                          const float* __restrict__ anc_wh,
                          const int* __restrict__ topk,
                          const int* __restrict__ cnt,
                          const int* __restrict__ agt,
                          int*   __restrict__ cls_arr,   // [BS*NG]
                          float* __restrict__ out_box,
                          float* __restrict__ out_anc,
                          float* __restrict__ out_fg)
{
    int t = blockIdx.x * blockDim.x + threadIdx.x;
    if (t < 6) out_anc[t] = anc_wh[t];
    if (t >= BS * NG) return;
    int b = t / NG;
    int g = t - b * NG;
    int c = cnt[t];
    int tgt = 0, fg = 0;
    if (c == 1) {
        tgt = agt[t]; fg = 1;
    } else if (c > 1) {
        // argmax over ALL gts of dist (first max wins, matching jnp.argmax)
        float gxc = (float)(g % GS) + 0.5f;
        float gyc = (float)(g / GS) + 0.5f;
        float best = -1.0f; int bi = 0;
        for (int n = 0; n < NMB; ++n) {
            float d = fabsf(gxc - gt_cxys[(b * NMB + n) * 2 + 0]) +
                      fabsf(gyc - gt_cxys[(b * NMB + n) * 2 + 1]);
            if (d > best) { best = d; bi = n; }
        }
        if (mask_gt[b * NMB + bi] > 0.0f) {
            const int* tk = topk + (b * NMB + bi) * 3;
            if (tk[0] == g || tk[1] == g || tk[2] == g) { tgt = bi; fg = 1; }
        }
    }
    int gi = b * NMB + tgt;
    int cls = (int)gt_cls[gi];
    cls_arr[t] = cls;
    float cx = gt_cxys[gi * 2 + 0], cy = gt_cxys[gi * 2 + 1];
    float w  = gt_whs[gi * 2 + 0],  h  = gt_whs[gi * 2 + 1];
    float gxf = (float)(g % GS), gyf = (float)(g / GS);
    float4 box = make_float4(cx - gxf, cy - gyf, w, h);
    float4* boxv = (float4*)out_box;
    #pragma unroll
    for (int a = 0; a < NANC; ++a) {
        boxv[(size_t)(b * NANC + a) * NG + g] = box;
        float aw = anc_wh[a * 2 + 0], ah = anc_wh[a * 2 + 1];
        float rw = w / aw, rh = h / ah;
        float m = fmaxf(fmaxf(rw, 1.0f / rw), fmaxf(rh, 1.0f / rh));
        out_fg[(size_t)(b * NANC + a) * NG + g] = (fg && (m < 4.0f)) ? 1.0f : 0.0f;
    }
}

// one thread per float4 of the one-hot scores (coalesced 16B stores)
__global__ void k_scores(const int* __restrict__ cls_arr, float4* __restrict__ out)
{
    int t = blockIdx.x * blockDim.x + threadIdx.x;
    if (t >= BS * NANC * NG * (NC / 4)) return;
    int r  = t % (NC / 4);        // which group of 4 classes
    int q  = t / (NC / 4);        // (b*NANC + a)*NG + g
    int g  = q % NG;
    int ba = q / NG;
    int b  = ba / NANC;
    int cls = cls_arr[b * NG + g];
    int c0 = r << 2;
    float4 v;
    v.x = (cls == c0 + 0) ? 1.0f : 0.0f;
    v.y = (cls == c0 + 1) ? 1.0f : 0.0f;
    v.z = (cls == c0 + 2) ? 1.0f : 0.0f;
    v.w = (cls == c0 + 3) ? 1.0f : 0.0f;
    out[t] = v;
}

extern "C" void kernel_launch(void* const* d_in, const int* in_sizes, int n_in,
                              void* d_out, int out_size, void* d_ws, size_t ws_size,
                              hipStream_t stream) {
    const float* anc_wh  = (const float*)d_in[0];
    // d_in[1] = grid (recomputed analytically on device)
    const float* gt_cls  = (const float*)d_in[2];
    const float* gt_cxys = (const float*)d_in[3];
    const float* gt_whs  = (const float*)d_in[4];
    const float* mask_gt = (const float*)d_in[5];

    float* out        = (float*)d_out;
    float* out_box    = out;                                        // 32*3*6400*4
    float* out_scores = out + (size_t)BS * NANC * NG * 4;           // 32*3*6400*80
    float* out_anc    = out_scores + (size_t)BS * NANC * NG * NC;   // 6
    float* out_fg     = out_anc + 6;                                // 32*3*6400

    char* ws   = (char*)d_ws;
    int*  cnt  = (int*)ws;                                          // BS*NG
    int*  agt  = (int*)(ws + (size_t)BS * NG * 4);                  // BS*NG
    int*  topk = (int*)(ws + (size_t)BS * NG * 8);                  // BS*NMB*3
    int*  cls  = (int*)(ws + (size_t)BS * NG * 8 + (size_t)BS * NMB * 3 * 4); // BS*NG

    hipMemsetAsync(cnt, 0, (size_t)BS * NG * 4, stream);

    // 1 wave per gt: 4096 waves
    k_topk<<<(BS * NMB * 64) / 256, 256, 0, stream>>>(gt_cxys, mask_gt, topk, cnt, agt);

    k_resolve<<<(BS * NG + 255) / 256, 256, 0, stream>>>(
        gt_cls, gt_cxys, gt_whs, mask_gt, anc_wh, topk, cnt, agt,
        cls, out_box, out_anc, out_fg);

    int n4 = BS * NANC * NG * (NC / 4);
    k_scores<<<(n4 + 255) / 256, 256, 0, stream>>>(cls, (float4*)out_scores);
}

// Round 2
// 55.403 us; speedup vs baseline: 1.2651x; 1.2651x over previous
//
#include <hip/hip_runtime.h>

#define BS   32
#define NMB  128
#define GS   80
#define NG   (GS * GS)
#define NANC 3
#define NC   80
#define CPB  16                 // cells per block
#define CHUNKS (NG / CPB)       // 400

typedef unsigned long long ull;

__global__ __launch_bounds__(256) void k_all(
    const float* __restrict__ anc_wh,
    const float* __restrict__ gt_cls,
    const float* __restrict__ gt_cxys,
    const float* __restrict__ gt_whs,
    const float* __restrict__ mask_gt,
    float* __restrict__ out_box,
    float* __restrict__ out_scores,
    float* __restrict__ out_anc,
    float* __restrict__ out_fg)
{
    __shared__ float2 s_cxy[NMB];
    __shared__ float2 s_wh[NMB];
    __shared__ int    s_cls[NMB];
    __shared__ float  s_mask[NMB];
    __shared__ int    s_top[NMB * 3];
    __shared__ int    s_cnt[CPB];
    __shared__ int    s_agt[CPB];
    __shared__ int    s_ccls[CPB];
    __shared__ float4 s_box[CPB];
    __shared__ float2 s_cwh[CPB];
    __shared__ int    s_fgf[CPB];

    int t = threadIdx.x;
    int b = blockIdx.x / CHUNKS;
    int chunk = blockIdx.x - b * CHUNKS;
    int g0 = chunk * CPB;

    if (t < CPB) { s_cnt[t] = 0; s_agt[t] = 0x7fffffff; }

    if (t < NMB) {
        int gi = b * NMB + t;
        float cx = gt_cxys[gi * 2 + 0];
        float cy = gt_cxys[gi * 2 + 1];
        s_cxy[t] = make_float2(cx, cy);
        s_wh[t]  = make_float2(gt_whs[gi * 2 + 0], gt_whs[gi * 2 + 1]);
        s_cls[t] = (int)gt_cls[gi];
        s_mask[t] = mask_gt[gi];
        // analytic top-3: true top-3 provably inside 5x5 clamped window
        int gx0 = (int)floorf(cx); gx0 = min(max(gx0, 0), GS - 1);
        int gy0 = (int)floorf(cy); gy0 = min(max(gy0, 0), GS - 1);
        int xlo = max(gx0 - 2, 0), xhi = min(gx0 + 2, GS - 1);
        int ylo = max(gy0 - 2, 0), yhi = min(gy0 + 2, GS - 1);
        ull k0 = ~0ull, k1 = ~0ull, k2 = ~0ull;
        for (int gy = ylo; gy <= yhi; ++gy) {
            for (int gx = xlo; gx <= xhi; ++gx) {
                // EXACT reference arithmetic: |(gx+0.5)-cx| + |(gy+0.5)-cy|
                float d = fabsf((float)gx + 0.5f - cx) + fabsf((float)gy + 0.5f - cy);
                ull key = ((ull)__float_as_uint(d) << 32) | (unsigned)(gy * GS + gx);
                if (key < k2) {
                    if (key < k1) { k2 = k1; if (key < k0) { k1 = k0; k0 = key; } else k1 = key; }
                    else k2 = key;
                }
            }
        }
        s_top[t * 3 + 0] = (int)(unsigned)(k0 & 0xffffffffu);
        s_top[t * 3 + 1] = (int)(unsigned)(k1 & 0xffffffffu);
        s_top[t * 3 + 2] = (int)(unsigned)(k2 & 0xffffffffu);
    }
    __syncthreads();

    // claims: 16 cells x 128 gts, LDS atomics
    for (int p = t; p < CPB * NMB; p += 256) {
        int i = p >> 7;            // p / 128
        int n = p & (NMB - 1);
        int g = g0 + i;
        if (s_mask[n] > 0.0f &&
            (s_top[n * 3] == g || s_top[n * 3 + 1] == g || s_top[n * 3 + 2] == g)) {
            atomicAdd(&s_cnt[i], 1);
            atomicMin(&s_agt[i], n);   // unique claimant when cnt==1
        }
    }
    __syncthreads();

    if (t < CPB) {
        int g = g0 + t;
        int c = s_cnt[t];
        int tgt = 0, fg = 0;
        if (c == 1) { tgt = s_agt[t]; fg = 1; }
        else if (c > 1) {
            // jnp.argmax over ALL gts of dist (first max wins)
            float gxc = (float)(g % GS) + 0.5f;
            float gyc = (float)(g / GS) + 0.5f;
            float best = -1.0f; int bi = 0;
            for (int n = 0; n < NMB; ++n) {
                float d = fabsf(gxc - s_cxy[n].x) + fabsf(gyc - s_cxy[n].y);
                if (d > best) { best = d; bi = n; }
            }
            if (s_mask[bi] > 0.0f &&
                (s_top[bi * 3] == g || s_top[bi * 3 + 1] == g || s_top[bi * 3 + 2] == g)) {
                tgt = bi; fg = 1;
            }
        }
        float cx = s_cxy[tgt].x, cy = s_cxy[tgt].y;
        float w = s_wh[tgt].x,  h = s_wh[tgt].y;
        float gxf = (float)(g % GS), gyf = (float)(g / GS);
        s_box[t] = make_float4(cx - gxf, cy - gyf, w, h);
        s_cwh[t] = make_float2(w, h);
        s_ccls[t] = s_cls[tgt];
        s_fgf[t] = fg;
    }
    __syncthreads();

    // one-hot scores: 3 anchors x 16 cells x 20 float4 = 960 float4, coalesced
    float4* sc4 = (float4*)out_scores;
    for (int f = t; f < NANC * CPB * (NC / 4); f += 256) {
        int a   = f / (CPB * (NC / 4));
        int rem = f - a * (CPB * (NC / 4));
        int i   = rem / (NC / 4);
        int r4  = rem - i * (NC / 4);
        int cls = s_ccls[i];
        int c0 = r4 << 2;
        float4 v;
        v.x = (cls == c0 + 0) ? 1.0f : 0.0f;
        v.y = (cls == c0 + 1) ? 1.0f : 0.0f;
        v.z = (cls == c0 + 2) ? 1.0f : 0.0f;
        v.w = (cls == c0 + 3) ? 1.0f : 0.0f;
        sc4[((size_t)(b * NANC + a) * NG + g0 + i) * (NC / 4) + r4] = v;
    }
    // box + fg
    if (t < NANC * CPB) {
        int a = t / CPB;
        int i = t - a * CPB;
        float4* bx4 = (float4*)out_box;
        bx4[(size_t)(b * NANC + a) * NG + g0 + i] = s_box[i];
        float aw = anc_wh[a * 2 + 0], ah = anc_wh[a * 2 + 1];
        float w = s_cwh[i].x, h = s_cwh[i].y;
        float rw = w / aw, rh = h / ah;    // then 1.0f/r exactly as reference
        float m = fmaxf(fmaxf(rw, 1.0f / rw), fmaxf(rh, 1.0f / rh));
        out_fg[(size_t)(b * NANC + a) * NG + g0 + i] = (s_fgf[i] && m < 4.0f) ? 1.0f : 0.0f;
    }
    if (blockIdx.x == 0 && t < 6) out_anc[t] = anc_wh[t];
}

extern "C" void kernel_launch(void* const* d_in, const int* in_sizes, int n_in,
                              void* d_out, int out_size, void* d_ws, size_t ws_size,
                              hipStream_t stream) {
    const float* anc_wh  = (const float*)d_in[0];
    // d_in[1] = grid (recomputed analytically on device)
    const float* gt_cls  = (const float*)d_in[2];
    const float* gt_cxys = (const float*)d_in[3];
    const float* gt_whs  = (const float*)d_in[4];
    const float* mask_gt = (const float*)d_in[5];

    float* out        = (float*)d_out;
    float* out_box    = out;                                        // 32*3*6400*4
    float* out_scores = out + (size_t)BS * NANC * NG * 4;           // 32*3*6400*80
    float* out_anc    = out_scores + (size_t)BS * NANC * NG * NC;   // 6
    float* out_fg     = out_anc + 6;                                // 32*3*6400

    k_all<<<BS * CHUNKS, 256, 0, stream>>>(
        anc_wh, gt_cls, gt_cxys, gt_whs, mask_gt,
        out_box, out_scores, out_anc, out_fg);
}

// Round 3
// 37.260 us; speedup vs baseline: 1.8811x; 1.4869x over previous
//
#include <hip/hip_runtime.h>

#define BS   32
#define NMB  128
#define GS   80
#define NG   (GS * GS)
#define NANC 3
#define NC   80
#define CPB  64                 // cells per block
#define CHUNKS (NG / CPB)       // 100

typedef unsigned long long ull;

__global__ __launch_bounds__(256) void k_all(
    const float* __restrict__ anc_wh,
    const float* __restrict__ gt_cls,
    const float* __restrict__ gt_cxys,
    const float* __restrict__ gt_whs,
    const float* __restrict__ mask_gt,
    float* __restrict__ out_box,
    float* __restrict__ out_scores,
    float* __restrict__ out_anc,
    float* __restrict__ out_fg)
{
    __shared__ float2 s_cxy[NMB];
    __shared__ float2 s_wh[NMB];
    __shared__ int    s_cls[NMB];
    __shared__ float  s_mask[NMB];
    __shared__ int    s_top[NMB * 3];
    __shared__ int    s_cnt[CPB];
    __shared__ int    s_agt[CPB];
    __shared__ int    s_ccls[CPB];
    __shared__ float4 s_box[CPB];
    __shared__ float2 s_cwh[CPB];
    __shared__ int    s_fgf[CPB];

    int t = threadIdx.x;
    int b = blockIdx.x / CHUNKS;
    int chunk = blockIdx.x - b * CHUNKS;
    int g0 = chunk * CPB;

    if (t >= 128 && t < 128 + CPB) { s_cnt[t - 128] = 0; s_agt[t - 128] = 0x7fffffff; }

    if (t < NMB) {
        int gi = b * NMB + t;
        float2 cxy = ((const float2*)gt_cxys)[gi];
        float cx = cxy.x, cy = cxy.y;
        s_cxy[t] = cxy;
        s_wh[t]  = ((const float2*)gt_whs)[gi];
        s_cls[t] = (int)gt_cls[gi];
        s_mask[t] = mask_gt[gi];
        // analytic top-3: true top-3 provably inside 5x5 clamped window
        int gx0 = (int)floorf(cx); gx0 = min(max(gx0, 0), GS - 1);
        int gy0 = (int)floorf(cy); gy0 = min(max(gy0, 0), GS - 1);
        int xlo = max(gx0 - 2, 0), xhi = min(gx0 + 2, GS - 1);
        int ylo = max(gy0 - 2, 0), yhi = min(gy0 + 2, GS - 1);
        ull k0 = ~0ull, k1 = ~0ull, k2 = ~0ull;
        for (int gy = ylo; gy <= yhi; ++gy) {
            for (int gx = xlo; gx <= xhi; ++gx) {
                // EXACT reference arithmetic: |(gx+0.5)-cx| + |(gy+0.5)-cy|
                float d = fabsf((float)gx + 0.5f - cx) + fabsf((float)gy + 0.5f - cy);
                ull key = ((ull)__float_as_uint(d) << 32) | (unsigned)(gy * GS + gx);
                if (key < k2) {
                    if (key < k1) { k2 = k1; if (key < k0) { k1 = k0; k0 = key; } else k1 = key; }
                    else k2 = key;
                }
            }
        }
        s_top[t * 3 + 0] = (int)(unsigned)(k0 & 0xffffffffu);
        s_top[t * 3 + 1] = (int)(unsigned)(k1 & 0xffffffffu);
        s_top[t * 3 + 2] = (int)(unsigned)(k2 & 0xffffffffu);
    }
    __syncthreads();

    // claims: each gt scatters its (up to) 3 claims that land in this chunk
    if (t < NMB && s_mask[t] > 0.0f) {
        #pragma unroll
        for (int j = 0; j < 3; ++j) {
            int i = s_top[t * 3 + j] - g0;
            if ((unsigned)i < (unsigned)CPB) {
                atomicAdd(&s_cnt[i], 1);
                atomicMin(&s_agt[i], t);   // unique claimant when cnt==1
            }
        }
    }
    __syncthreads();

    if (t < CPB) {
        int g = g0 + t;
        int c = s_cnt[t];
        int tgt = 0, fg = 0;
        if (c == 1) { tgt = s_agt[t]; fg = 1; }
        else if (c > 1) {
            // jnp.argmax over ALL gts of dist (first max wins)
            float gxc = (float)(g % GS) + 0.5f;
            float gyc = (float)(g / GS) + 0.5f;
            float best = -1.0f; int bi = 0;
            for (int n = 0; n < NMB; ++n) {
                float d = fabsf(gxc - s_cxy[n].x) + fabsf(gyc - s_cxy[n].y);
                if (d > best) { best = d; bi = n; }
            }
            if (s_mask[bi] > 0.0f &&
                (s_top[bi * 3] == g || s_top[bi * 3 + 1] == g || s_top[bi * 3 + 2] == g)) {
                tgt = bi; fg = 1;
            }
        }
        float cx = s_cxy[tgt].x, cy = s_cxy[tgt].y;
        float w = s_wh[tgt].x,  h = s_wh[tgt].y;
        float gxf = (float)(g % GS), gyf = (float)(g / GS);
        s_box[t] = make_float4(cx - gxf, cy - gyf, w, h);
        s_cwh[t] = make_float2(w, h);
        s_ccls[t] = s_cls[tgt];
        s_fgf[t] = fg;
    }
    __syncthreads();

    // one-hot scores: 3 anchors x 64 cells x 20 float4 = 3840 float4 (15/thread)
    float4* sc4 = (float4*)out_scores;
    for (int f = t; f < NANC * CPB * (NC / 4); f += 256) {
        int a   = f / (CPB * (NC / 4));
        int rem = f - a * (CPB * (NC / 4));
        int i   = rem / (NC / 4);
        int r4  = rem - i * (NC / 4);
        int cls = s_ccls[i];
        int c0 = r4 << 2;
        float4 v;
        v.x = (cls == c0 + 0) ? 1.0f : 0.0f;
        v.y = (cls == c0 + 1) ? 1.0f : 0.0f;
        v.z = (cls == c0 + 2) ? 1.0f : 0.0f;
        v.w = (cls == c0 + 3) ? 1.0f : 0.0f;
        sc4[((size_t)(b * NANC + a) * NG + g0 + i) * (NC / 4) + r4] = v;
    }
    // box (float4) + fg (scalar): 3 anchors x 64 cells = 192
    if (t < NANC * CPB) {
        int a = t / CPB;
        int i = t - a * CPB;
        float4* bx4 = (float4*)out_box;
        bx4[(size_t)(b * NANC + a) * NG + g0 + i] = s_box[i];
        float aw = anc_wh[a * 2 + 0], ah = anc_wh[a * 2 + 1];
        float w = s_cwh[i].x, h = s_cwh[i].y;
        float rw = w / aw, rh = h / ah;
        float m = fmaxf(fmaxf(rw, 1.0f / rw), fmaxf(rh, 1.0f / rh));
        out_fg[(size_t)(b * NANC + a) * NG + g0 + i] = (s_fgf[i] && m < 4.0f) ? 1.0f : 0.0f;
    }
    if (blockIdx.x == 0 && t < 6) out_anc[t] = anc_wh[t];
}

extern "C" void kernel_launch(void* const* d_in, const int* in_sizes, int n_in,
                              void* d_out, int out_size, void* d_ws, size_t ws_size,
                              hipStream_t stream) {
    const float* anc_wh  = (const float*)d_in[0];
    // d_in[1] = grid (recomputed analytically on device)
    const float* gt_cls  = (const float*)d_in[2];
    const float* gt_cxys = (const float*)d_in[3];
    const float* gt_whs  = (const float*)d_in[4];
    const float* mask_gt = (const float*)d_in[5];

    float* out        = (float*)d_out;
    float* out_box    = out;                                        // 32*3*6400*4
    float* out_scores = out + (size_t)BS * NANC * NG * 4;           // 32*3*6400*80
    float* out_anc    = out_scores + (size_t)BS * NANC * NG * NC;   // 6
    float* out_fg     = out_anc + 6;                                // 32*3*6400

    k_all<<<BS * CHUNKS, 256, 0, stream>>>(
        anc_wh, gt_cls, gt_cxys, gt_whs, mask_gt,
        out_box, out_scores, out_anc, out_fg);
}

// Round 4
// 37.027 us; speedup vs baseline: 1.8929x; 1.0063x over previous
//
#include <hip/hip_runtime.h>

#define BS   32
#define NMB  128
#define GS   80
#define NG   (GS * GS)
#define NANC 3
#define NC   80
#define CPB  128                // cells per block
#define CHUNKS (NG / CPB)       // 50

typedef unsigned long long ull;

__global__ __launch_bounds__(256) void k_all(
    const float* __restrict__ anc_wh,
    const float* __restrict__ gt_cls,
    const float* __restrict__ gt_cxys,
    const float* __restrict__ gt_whs,
    const float* __restrict__ mask_gt,
    float* __restrict__ out_box,
    float* __restrict__ out_scores,
    float* __restrict__ out_anc,
    float* __restrict__ out_fg)
{
    __shared__ float2 s_cxy[NMB];
    __shared__ float2 s_wh[NMB];
    __shared__ int    s_cls[NMB];
    __shared__ float  s_mask[NMB];
    __shared__ int    s_top[NMB * 3];
    __shared__ int    s_cnt[CPB];
    __shared__ int    s_agt[CPB];
    __shared__ int    s_ccls[CPB];

    int t = threadIdx.x;
    int b = blockIdx.x / CHUNKS;
    int chunk = blockIdx.x - b * CHUNKS;
    int g0 = chunk * CPB;

    if (t >= 128) { s_cnt[t - 128] = 0; s_agt[t - 128] = 0x7fffffff; }

    if (t < NMB) {
        int gi = b * NMB + t;
        float2 cxy = ((const float2*)gt_cxys)[gi];
        float cx = cxy.x, cy = cxy.y;
        s_cxy[t] = cxy;
        s_wh[t]  = ((const float2*)gt_whs)[gi];
        s_cls[t] = (int)gt_cls[gi];
        s_mask[t] = mask_gt[gi];
        // analytic top-3: true top-3 provably inside 5x5 clamped window
        int gx0 = (int)floorf(cx); gx0 = min(max(gx0, 0), GS - 1);
        int gy0 = (int)floorf(cy); gy0 = min(max(gy0, 0), GS - 1);
        int xlo = max(gx0 - 2, 0), xhi = min(gx0 + 2, GS - 1);
        int ylo = max(gy0 - 2, 0), yhi = min(gy0 + 2, GS - 1);
        ull k0 = ~0ull, k1 = ~0ull, k2 = ~0ull;
        for (int gy = ylo; gy <= yhi; ++gy) {
            for (int gx = xlo; gx <= xhi; ++gx) {
                // EXACT reference arithmetic: |(gx+0.5)-cx| + |(gy+0.5)-cy|
                float d = fabsf((float)gx + 0.5f - cx) + fabsf((float)gy + 0.5f - cy);
                ull key = ((ull)__float_as_uint(d) << 32) | (unsigned)(gy * GS + gx);
                if (key < k2) {
                    if (key < k1) { k2 = k1; if (key < k0) { k1 = k0; k0 = key; } else k1 = key; }
                    else k2 = key;
                }
            }
        }
        s_top[t * 3 + 0] = (int)(unsigned)(k0 & 0xffffffffu);
        s_top[t * 3 + 1] = (int)(unsigned)(k1 & 0xffffffffu);
        s_top[t * 3 + 2] = (int)(unsigned)(k2 & 0xffffffffu);
    }
    __syncthreads();

    // claims: each gt scatters its (up to) 3 claims that land in this chunk
    if (t < NMB && s_mask[t] > 0.0f) {
        #pragma unroll
        for (int j = 0; j < 3; ++j) {
            int i = s_top[t * 3 + j] - g0;
            if ((unsigned)i < (unsigned)CPB) {
                atomicAdd(&s_cnt[i], 1);
                atomicMin(&s_agt[i], t);   // unique claimant when cnt==1
            }
        }
    }
    __syncthreads();

    // resolve + direct box/fg writes (t == cell index, 128 contiguous lanes)
    if (t < CPB) {
        int g = g0 + t;
        int c = s_cnt[t];
        int tgt = 0, fg = 0;
        if (c == 1) { tgt = s_agt[t]; fg = 1; }
        else if (c > 1) {
            // jnp.argmax over ALL gts of dist (first max wins)
            float gxc = (float)(g % GS) + 0.5f;
            float gyc = (float)(g / GS) + 0.5f;
            float best = -1.0f; int bi = 0;
            for (int n = 0; n < NMB; ++n) {
                float d = fabsf(gxc - s_cxy[n].x) + fabsf(gyc - s_cxy[n].y);
                if (d > best) { best = d; bi = n; }
            }
            if (s_mask[bi] > 0.0f &&
                (s_top[bi * 3] == g || s_top[bi * 3 + 1] == g || s_top[bi * 3 + 2] == g)) {
                tgt = bi; fg = 1;
            }
        }
        s_ccls[t] = s_cls[tgt];
        float cx = s_cxy[tgt].x, cy = s_cxy[tgt].y;
        float w = s_wh[tgt].x,  h = s_wh[tgt].y;
        float gxf = (float)(g % GS), gyf = (float)(g / GS);
        float4 box = make_float4(cx - gxf, cy - gyf, w, h);
        float4* bx4 = (float4*)out_box;
        #pragma unroll
        for (int a = 0; a < NANC; ++a) {
            bx4[(size_t)(b * NANC + a) * NG + g] = box;
            float aw = anc_wh[a * 2 + 0], ah = anc_wh[a * 2 + 1];
            float rw = w / aw, rh = h / ah;   // exact reference op order
            float m = fmaxf(fmaxf(rw, 1.0f / rw), fmaxf(rh, 1.0f / rh));
            out_fg[(size_t)(b * NANC + a) * NG + g] = (fg && m < 4.0f) ? 1.0f : 0.0f;
        }
    }
    __syncthreads();

    // one-hot scores: 3 anchors x 128 cells x 20 float4 = 7680 float4 (30/thread)
    float4* sc4 = (float4*)out_scores;
    for (int f = t; f < NANC * CPB * (NC / 4); f += 256) {
        int a   = f / (CPB * (NC / 4));
        int rem = f - a * (CPB * (NC / 4));
        int i   = rem / (NC / 4);
        int r4  = rem - i * (NC / 4);
        int cls = s_ccls[i];
        int c0 = r4 << 2;
        float4 v;
        v.x = (cls == c0 + 0) ? 1.0f : 0.0f;
        v.y = (cls == c0 + 1) ? 1.0f : 0.0f;
        v.z = (cls == c0 + 2) ? 1.0f : 0.0f;
        v.w = (cls == c0 + 3) ? 1.0f : 0.0f;
        sc4[((size_t)(b * NANC + a) * NG + g0 + i) * (NC / 4) + r4] = v;
    }
    if (blockIdx.x == 0 && t < 6) out_anc[t] = anc_wh[t];
}

extern "C" void kernel_launch(void* const* d_in, const int* in_sizes, int n_in,
                              void* d_out, int out_size, void* d_ws, size_t ws_size,
                              hipStream_t stream) {
    const float* anc_wh  = (const float*)d_in[0];
    // d_in[1] = grid (recomputed analytically on device)
    const float* gt_cls  = (const float*)d_in[2];
    const float* gt_cxys = (const float*)d_in[3];
    const float* gt_whs  = (const float*)d_in[4];
    const float* mask_gt = (const float*)d_in[5];

    float* out        = (float*)d_out;
    float* out_box    = out;                                        // 32*3*6400*4
    float* out_scores = out + (size_t)BS * NANC * NG * 4;           // 32*3*6400*80
    float* out_anc    = out_scores + (size_t)BS * NANC * NG * NC;   // 6
    float* out_fg     = out_anc + 6;                                // 32*3*6400

    k_all<<<BS * CHUNKS, 256, 0, stream>>>(
        anc_wh, gt_cls, gt_cxys, gt_whs, mask_gt,
        out_box, out_scores, out_anc, out_fg);
}

// Round 5
// 36.475 us; speedup vs baseline: 1.9216x; 1.0151x over previous
//
#include <hip/hip_runtime.h>

#define BS   32
#define NMB  128
#define GS   80
#define NG   (GS * GS)
#define NANC 3
#define NC   80
#define CPB  100                // cells per block
#define CHUNKS (NG / CPB)       // 64  -> grid = 32*64 = 2048 = exactly 8 blocks/CU

typedef unsigned long long ull;

__global__ __launch_bounds__(256) void k_all(
    const float* __restrict__ anc_wh,
    const float* __restrict__ gt_cls,
    const float* __restrict__ gt_cxys,
    const float* __restrict__ gt_whs,
    const float* __restrict__ mask_gt,
    float* __restrict__ out_box,
    float* __restrict__ out_scores,
    float* __restrict__ out_anc,
    float* __restrict__ out_fg)
{
    __shared__ float2 s_cxy[NMB];
    __shared__ float2 s_wh[NMB];
    __shared__ int    s_cls[NMB];
    __shared__ float  s_mask[NMB];
    __shared__ int    s_top[NMB * 3];
    __shared__ int    s_cnt[CPB];
    __shared__ int    s_agt[CPB];
    __shared__ int    s_ccls[CPB];

    int t = threadIdx.x;
    int b = blockIdx.x >> 6;            // / CHUNKS (=64)
    int chunk = blockIdx.x & 63;
    int g0 = chunk * CPB;

    if (t >= 128 && t < 128 + CPB) { s_cnt[t - 128] = 0; s_agt[t - 128] = 0x7fffffff; }

    if (t < NMB) {
        int gi = b * NMB + t;
        float2 cxy = ((const float2*)gt_cxys)[gi];
        float cx = cxy.x, cy = cxy.y;
        s_cxy[t] = cxy;
        s_wh[t]  = ((const float2*)gt_whs)[gi];
        s_cls[t] = (int)gt_cls[gi];
        s_mask[t] = mask_gt[gi];
        // analytic top-3: true top-3 provably inside 5x5 clamped window
        int gx0 = (int)floorf(cx); gx0 = min(max(gx0, 0), GS - 1);
        int gy0 = (int)floorf(cy); gy0 = min(max(gy0, 0), GS - 1);
        int xlo = max(gx0 - 2, 0), xhi = min(gx0 + 2, GS - 1);
        int ylo = max(gy0 - 2, 0), yhi = min(gy0 + 2, GS - 1);
        ull k0 = ~0ull, k1 = ~0ull, k2 = ~0ull;
        for (int gy = ylo; gy <= yhi; ++gy) {
            for (int gx = xlo; gx <= xhi; ++gx) {
                // EXACT reference arithmetic: |(gx+0.5)-cx| + |(gy+0.5)-cy|
                float d = fabsf((float)gx + 0.5f - cx) + fabsf((float)gy + 0.5f - cy);
                ull key = ((ull)__float_as_uint(d) << 32) | (unsigned)(gy * GS + gx);
                if (key < k2) {
                    if (key < k1) { k2 = k1; if (key < k0) { k1 = k0; k0 = key; } else k1 = key; }
                    else k2 = key;
                }
            }
        }
        s_top[t * 3 + 0] = (int)(unsigned)(k0 & 0xffffffffu);
        s_top[t * 3 + 1] = (int)(unsigned)(k1 & 0xffffffffu);
        s_top[t * 3 + 2] = (int)(unsigned)(k2 & 0xffffffffu);
    }
    __syncthreads();

    // claims: each gt scatters its (up to) 3 claims that land in this chunk
    if (t < NMB && s_mask[t] > 0.0f) {
        #pragma unroll
        for (int j = 0; j < 3; ++j) {
            int i = s_top[t * 3 + j] - g0;
            if ((unsigned)i < (unsigned)CPB) {
                atomicAdd(&s_cnt[i], 1);
                atomicMin(&s_agt[i], t);   // unique claimant when cnt==1
            }
        }
    }
    __syncthreads();

    // resolve + direct box/fg writes (t == cell index, contiguous lanes)
    if (t < CPB) {
        int g = g0 + t;
        int c = s_cnt[t];
        int tgt = 0, fg = 0;
        if (c == 1) { tgt = s_agt[t]; fg = 1; }
        else if (c > 1) {
            // jnp.argmax over ALL gts of dist (first max wins)
            float gxc = (float)(g % GS) + 0.5f;
            float gyc = (float)(g / GS) + 0.5f;
            float best = -1.0f; int bi = 0;
            for (int n = 0; n < NMB; ++n) {
                float d = fabsf(gxc - s_cxy[n].x) + fabsf(gyc - s_cxy[n].y);
                if (d > best) { best = d; bi = n; }
            }
            if (s_mask[bi] > 0.0f &&
                (s_top[bi * 3] == g || s_top[bi * 3 + 1] == g || s_top[bi * 3 + 2] == g)) {
                tgt = bi; fg = 1;
            }
        }
        s_ccls[t] = s_cls[tgt];
        float cx = s_cxy[tgt].x, cy = s_cxy[tgt].y;
        float w = s_wh[tgt].x,  h = s_wh[tgt].y;
        float gxf = (float)(g % GS), gyf = (float)(g / GS);
        float4 box = make_float4(cx - gxf, cy - gyf, w, h);
        float4* bx4 = (float4*)out_box;
        #pragma unroll
        for (int a = 0; a < NANC; ++a) {
            bx4[(size_t)(b * NANC + a) * NG + g] = box;
            float aw = anc_wh[a * 2 + 0], ah = anc_wh[a * 2 + 1];
            float rw = w / aw, rh = h / ah;   // exact reference op order
            float m = fmaxf(fmaxf(rw, 1.0f / rw), fmaxf(rh, 1.0f / rh));
            out_fg[(size_t)(b * NANC + a) * NG + g] = (fg && m < 4.0f) ? 1.0f : 0.0f;
        }
    }
    __syncthreads();

    // one-hot scores: 3 anchors x 100 cells x 20 float4 = 6000 float4 (~23/thread)
    float4* sc4 = (float4*)out_scores;
    for (int f = t; f < NANC * CPB * (NC / 4); f += 256) {
        int a   = f / (CPB * (NC / 4));
        int rem = f - a * (CPB * (NC / 4));
        int i   = rem / (NC / 4);
        int r4  = rem - i * (NC / 4);
        int cls = s_ccls[i];
        int c0 = r4 << 2;
        float4 v;
        v.x = (cls == c0 + 0) ? 1.0f : 0.0f;
        v.y = (cls == c0 + 1) ? 1.0f : 0.0f;
        v.z = (cls == c0 + 2) ? 1.0f : 0.0f;
        v.w = (cls == c0 + 3) ? 1.0f : 0.0f;
        sc4[((size_t)(b * NANC + a) * NG + g0 + i) * (NC / 4) + r4] = v;
    }
    if (blockIdx.x == 0 && t < 6) out_anc[t] = anc_wh[t];
}

extern "C" void kernel_launch(void* const* d_in, const int* in_sizes, int n_in,
                              void* d_out, int out_size, void* d_ws, size_t ws_size,
                              hipStream_t stream) {
    const float* anc_wh  = (const float*)d_in[0];
    // d_in[1] = grid (recomputed analytically on device)
    const float* gt_cls  = (const float*)d_in[2];
    const float* gt_cxys = (const float*)d_in[3];
    const float* gt_whs  = (const float*)d_in[4];
    const float* mask_gt = (const float*)d_in[5];

    float* out        = (float*)d_out;
    float* out_box    = out;                                        // 32*3*6400*4
    float* out_scores = out + (size_t)BS * NANC * NG * 4;           // 32*3*6400*80
    float* out_anc    = out_scores + (size_t)BS * NANC * NG * NC;   // 6
    float* out_fg     = out_anc + 6;                                // 32*3*6400

    k_all<<<BS * CHUNKS, 256, 0, stream>>>(
        anc_wh, gt_cls, gt_cxys, gt_whs, mask_gt,
        out_box, out_scores, out_anc, out_fg);
}